// Round 3
// baseline (330.016 us; speedup 1.0000x reference)
//
#include <hip/hip_runtime.h>

// x: [2,64,32,32,32] f32 | weight: [128,64,3,3,3] f32 | bias:[128]
// lora_A: [16,1728] | lora_B: [128,16] | out: [2,128,32,32,32] f32 | SCALING = 2.0

typedef __attribute__((ext_vector_type(8))) short short8;
typedef __attribute__((ext_vector_type(4))) float float4v;

#define PV 39304   // 34^3
#define PH 1156    // 34^2
#define NBLK 512u

__device__ inline unsigned short f2bf(float f) {
    unsigned int u = __float_as_uint(f);
    unsigned int r = u + 0x7FFFu + ((u >> 16) & 1u);
    return (unsigned short)(r >> 16);
}

__device__ inline void gll16(const void* g, void* l) {
    __builtin_amdgcn_global_load_lds(
        (const __attribute__((address_space(1))) unsigned int*)g,
        (__attribute__((address_space(3))) unsigned int*)l, 16, 0, 0);
}

// Software grid barrier. Counters zeroed by hipMemsetAsync before launch each
// iteration. Release: __threadfence (agent scope), device-scope atomicAdd;
// acquire: agent-scope atomic load + __threadfence.
// Co-residency: __launch_bounds__(256,2) -> 2 blocks/CU (VGPR cap 256, no
// inner-loop spill; LDS 36.9KB <= 80KB). 2 x 256 CU = 512 = grid, no deadlock.
__device__ inline void grid_barrier(unsigned int* bar, int slot) {
    __syncthreads();
    if (threadIdx.x == 0) {
        __threadfence();
        unsigned int* c = bar + slot * 32;   // 128B apart
        atomicAdd(c, 1u);
        while (__hip_atomic_load(c, __ATOMIC_ACQUIRE, __HIP_MEMORY_SCOPE_AGENT) < NBLK) {
            __builtin_amdgcn_s_sleep(2);
        }
    }
    __syncthreads();
    __threadfence();
}

// ===================== fused kernel (3 phases, 2 grid barriers) =============
__global__ __launch_bounds__(256, 2) void fused_kernel(
    const float* __restrict__ x, const float* __restrict__ weight,
    const float* __restrict__ bias, const float* __restrict__ loraA,
    const float* __restrict__ loraB, float* __restrict__ out,
    unsigned short* __restrict__ xt, unsigned short* __restrict__ wpack,
    float* __restrict__ low, unsigned int* __restrict__ bar)
{
    __shared__ __align__(16) char smraw[36864];   // union: tile / Abuf / fl+lBp+bias
    int t = threadIdx.x;
    int bid = blockIdx.x;

    // ---------------- Phase 1: prep (1454 units strided over 512 blocks) ----
    {
        float (*tile)[65] = (float (*)[65])smraw;
        for (int u = bid; u < 1454; u += 512) {
            if (u < 1024) {
                int pb = u >> 9;
                int p0 = (u & 511) * 64;
                int pd = p0 >> 10;
                int ph0 = (p0 >> 5) & 31;
#pragma unroll
                for (int it = 0; it < 16; ++it) {
                    int idx = it * 256 + t;
                    int c = idx >> 6, pp = idx & 63;
                    tile[c][pp] = x[((size_t)(pb * 64 + c) << 15) + p0 + pp];
                }
                __syncthreads();
#pragma unroll
                for (int it = 0; it < 8; ++it) {
                    int idx = it * 256 + t;
                    int pp = idx >> 5, cp = idx & 31;
                    unsigned int u0 = f2bf(tile[cp * 2][pp]);
                    unsigned int u1 = f2bf(tile[cp * 2 + 1][pp]);
                    int ph = ph0 + (pp >> 5);
                    int pw = pp & 31;
                    size_t pidx = (size_t)((pb * 34 + pd + 1) * 34 + ph + 1) * 34 + pw + 1;
                    *(unsigned int*)(xt + pidx * 64 + cp * 2) = u0 | (u1 << 16);
                }
            } else if (u < 1332) {
                int idx = (u - 1024) * 256 + t;     // over 2*39304 padded positions
                if (idx < 78608) {
                    int pb = idx / PV;
                    int pp = idx - pb * PV;
                    int pd = pp / PH;
                    int r2 = pp - pd * PH;
                    int ph = r2 / 34;
                    int pw = r2 - ph * 34;
                    if (pd == 0 || pd == 33 || ph == 0 || ph == 33 || pw == 0 || pw == 33) {
                        uint4 z = {0u, 0u, 0u, 0u};
                        uint4* dst = (uint4*)(xt + (size_t)idx * 64);
#pragma unroll
                        for (int i = 0; i < 8; ++i) dst[i] = z;
                    }
                }
            } else {
                int gid = (u - 1332) * 256 + t;     // 486 frags * 64 lanes = 31104
                if (gid < 31104) {
                    int frag = gid >> 6, ln = gid & 63;
                    int kb = frag / 18;
                    int r18 = frag - kb * 18;
                    int ks = r18 / 9;
                    int nf = r18 - ks * 9;
                    int pl16 = ln & 15, pq = ln >> 4;
                    int n = nf * 16 + pl16;
                    int c0 = ks * 32 + pq * 8;
                    unsigned int uu[4];
#pragma unroll
                    for (int jp = 0; jp < 4; ++jp) {
                        int ca = c0 + jp * 2, cb = ca + 1;
                        float v0, v1;
                        if (n < 128) {
                            v0 = weight[(n * 64 + ca) * 27 + kb];
                            v1 = weight[(n * 64 + cb) * 27 + kb];
                        } else {
                            v0 = loraA[(n - 128) * 1728 + ca * 27 + kb];
                            v1 = loraA[(n - 128) * 1728 + cb * 27 + kb];
                        }
                        uu[jp] = (unsigned)f2bf(v0) | ((unsigned)f2bf(v1) << 16);
                    }
                    uint4 val; val.x = uu[0]; val.y = uu[1]; val.z = uu[2]; val.w = uu[3];
                    *(uint4*)(wpack + (size_t)gid * 8) = val;
                }
            }
            __syncthreads();
        }
    }

    grid_barrier(bar, 0);

    // ---------------- Phase 2: implicit GEMM (verified inner loop) ----------
    int wv = t >> 6;
    int lane = t & 63;
    int l16 = lane & 15;
    int quad = lane >> 4;

    int tl = ((bid & 7) << 6) | (bid >> 3);   // XCD d-slab locality (bijective on 512)
    int b = tl >> 8;
    int d = (tl >> 3) & 31;
    int hb = (tl & 7) << 2;
    int h = hb + wv;

    unsigned short (*Abuf)[9216] = (unsigned short (*)[9216])smraw;

    int pbase = (((b * 34 + d) * 34 + h) * 34 + l16) * 64 + quad * 8;

    float4v acc[9][2];
#pragma unroll
    for (int nf = 0; nf < 9; ++nf)
#pragma unroll
        for (int f = 0; f < 2; ++f) acc[nf][f] = (float4v){0.f, 0.f, 0.f, 0.f};

    short8 breg[2][2][2];    // [buf][ks][f]

    auto prefA = [&](int tap, int buf) {
        const unsigned short* src = wpack + tap * 9216;   // 18432 B per tap
        unsigned short* dst = &Abuf[buf][0];
#pragma unroll
        for (int j = 0; j < 4; ++j) {
            int c8 = (t + j * 256) * 8;
            gll16(src + c8, dst + c8);
        }
        if (t < 128) {
            int c8 = (t + 1024) * 8;
            gll16(src + c8, dst + c8);
        }
    };
    auto loadB = [&](int tap, int buf) {
        int ki = tap / 9;
        int kjl = tap - ki * 9;
        int kj = kjl / 3;
        int kl = kjl - kj * 3;
        int koff = ki * 73984 + kj * 2176 + kl * 64;
        const unsigned short* xp = xt + pbase + koff;
        breg[buf][0][0] = *(const short8*)(xp);
        breg[buf][0][1] = *(const short8*)(xp + 1024);
        breg[buf][1][0] = *(const short8*)(xp + 32);
        breg[buf][1][1] = *(const short8*)(xp + 1056);
    };

    prefA(0, 0);
    loadB(0, 0);
    __syncthreads();

    for (int tap = 0; tap < 27; ++tap) {
        int cur = tap & 1, nxt = cur ^ 1;
        if (tap < 26) {
            prefA(tap + 1, nxt);
            loadB(tap + 1, nxt);
        }
        const unsigned short* ab = &Abuf[cur][0] + lane * 8;
#pragma unroll
        for (int ks = 0; ks < 2; ++ks) {
            short8 af[9];
#pragma unroll
            for (int nf = 0; nf < 9; ++nf)
                af[nf] = *(const short8*)(ab + (ks * 9 + nf) * 512);
#pragma unroll
            for (int nf = 0; nf < 9; ++nf) {
                acc[nf][0] = __builtin_amdgcn_mfma_f32_16x16x32_bf16(af[nf], breg[cur][ks][0], acc[nf][0], 0, 0, 0);
                acc[nf][1] = __builtin_amdgcn_mfma_f32_16x16x32_bf16(af[nf], breg[cur][ks][1], acc[nf][1], 0, 0, 0);
            }
        }
        __syncthreads();
    }

    // rank channels -> low (conv channels stay in acc registers)
    {
        int p = d * 1024 + h * 32;
#pragma unroll
        for (int f = 0; f < 2; ++f)
#pragma unroll
            for (int r = 0; r < 4; ++r)
                low[((size_t)(b * 16 + quad * 4 + r) << 15) + p + f * 16 + l16] = acc[8][f][r];
    }

    grid_barrier(bar, 1);

    // ---------------- Phase 3: fold + mix + store ---------------------------
    {
        float* fl  = (float*)smraw;            // [16][128] folded low, block-local
        float* lBp = (float*)(smraw + 8192);   // [16][128] = 2*lora_B transposed
        float* bsh = (float*)(smraw + 16384);  // [128] bias

        for (int i = t; i < 2048; i += 256) {
            int o = i & 127, rr = i >> 7;
            lBp[rr * 128 + o] = 2.0f * loraB[o * 16 + rr];
        }
        if (t < 128) bsh[t] = bias[t];

        {
            int pair = t & 63, rg = t >> 6;     // 2 consecutive w positions, 4 ranks
            int lp = pair * 2;
            int hh = hb + (lp >> 5);
            int w0 = lp & 31;                   // even
            float s0[4], s1[4];
#pragma unroll
            for (int r = 0; r < 4; ++r) { s0[r] = 0.f; s1[r] = 0.f; }
            const float* bb = low + ((size_t)(b * 16 + rg * 4) << 15);
            for (int dd = -1; dd <= 1; ++dd) {
                int sd = d + dd;
                if ((unsigned)sd >= 32u) continue;
                for (int dh = -1; dh <= 1; ++dh) {
                    int sh = hh + dh;
                    if ((unsigned)sh >= 32u) continue;
                    int base = (sd << 10) + (sh << 5) + w0;
#pragma unroll
                    for (int r = 0; r < 4; ++r) {
                        const float* q = bb + ((size_t)r << 15) + base;
                        float vm = (w0 > 0)  ? q[-1] : 0.f;
                        float v0 = q[0], v1 = q[1];
                        float v2 = (w0 < 30) ? q[2] : 0.f;
                        s0[r] += vm + v0 + v1;
                        s1[r] += v0 + v1 + v2;
                    }
                }
            }
#pragma unroll
            for (int r = 0; r < 4; ++r) {
                fl[(rg * 4 + r) * 128 + lp]     = s0[r];
                fl[(rg * 4 + r) * 128 + lp + 1] = s1[r];
            }
        }
        __syncthreads();

        float fa[16], fb[16];
        int base0 = wv * 32 + l16;
#pragma unroll
        for (int rr = 0; rr < 16; ++rr) {
            fa[rr] = fl[rr * 128 + base0];
            fb[rr] = fl[rr * 128 + base0 + 16];
        }
#pragma unroll
        for (int nf = 0; nf < 8; ++nf) {
            float4v sv0 = (float4v){0.f, 0.f, 0.f, 0.f};
            float4v sv1 = (float4v){0.f, 0.f, 0.f, 0.f};
#pragma unroll
            for (int rr = 0; rr < 16; ++rr) {
                float4v lw = *(const float4v*)&lBp[rr * 128 + nf * 16 + quad * 4];
                sv0 += lw * fa[rr];
                sv1 += lw * fb[rr];
            }
            size_t ob0 = ((size_t)(b * 128 + nf * 16 + quad * 4) << 15) + (size_t)(d * 1024 + h * 32);
#pragma unroll
            for (int r = 0; r < 4; ++r) {
                float bv = bsh[nf * 16 + quad * 4 + r];
                out[ob0 + ((size_t)r << 15) + l16]      = acc[nf][0][r] + bv + sv0[r];
                out[ob0 + ((size_t)r << 15) + 16 + l16] = acc[nf][1][r] + bv + sv1[r];
            }
        }
    }
}

// ===================== fallback: verified 3-kernel path =====================

__global__ __launch_bounds__(256) void prep_kernel(const float* __restrict__ x,
                                                   const float* __restrict__ weight,
                                                   const float* __restrict__ loraA,
                                                   unsigned short* __restrict__ xt,
                                                   unsigned short* __restrict__ wpack) {
    int t = threadIdx.x;
    int blk = blockIdx.x;
    if (blk < 1024) {
        __shared__ float tile[64][65];
        int b = blk >> 9;
        int p0 = (blk & 511) * 64;
        int d = p0 >> 10;
        int h0 = (p0 >> 5) & 31;
#pragma unroll
        for (int it = 0; it < 16; ++it) {
            int idx = it * 256 + t;
            int c = idx >> 6, pp = idx & 63;
            tile[c][pp] = x[((size_t)(b * 64 + c) << 15) + p0 + pp];
        }
        __syncthreads();
#pragma unroll
        for (int it = 0; it < 8; ++it) {
            int idx = it * 256 + t;
            int pp = idx >> 5, cp = idx & 31;
            unsigned int u0 = f2bf(tile[cp * 2][pp]);
            unsigned int u1 = f2bf(tile[cp * 2 + 1][pp]);
            int h = h0 + (pp >> 5);
            int w = pp & 31;
            size_t pidx = (size_t)((b * 34 + d + 1) * 34 + h + 1) * 34 + w + 1;
            *(unsigned int*)(xt + pidx * 64 + cp * 2) = u0 | (u1 << 16);
        }
    } else if (blk < 1332) {
        int idx = (blk - 1024) * 256 + t;
        if (idx < 78608) {
            int b = idx / PV;
            int pp = idx - b * PV;
            int d = pp / PH;
            int r2 = pp - d * PH;
            int h = r2 / 34;
            int w = r2 - h * 34;
            if (d == 0 || d == 33 || h == 0 || h == 33 || w == 0 || w == 33) {
                uint4 z = {0u, 0u, 0u, 0u};
                uint4* dst = (uint4*)(xt + (size_t)idx * 64);
#pragma unroll
                for (int i = 0; i < 8; ++i) dst[i] = z;
            }
        }
    } else {
        int gid = (blk - 1332) * 256 + t;
        if (gid < 31104) {
            int frag = gid >> 6, lane = gid & 63;
            int kb = frag / 18;
            int r18 = frag - kb * 18;
            int ks = r18 / 9;
            int nf = r18 - ks * 9;
            int l16 = lane & 15, quad = lane >> 4;
            int n = nf * 16 + l16;
            int c0 = ks * 32 + quad * 8;
            unsigned int u[4];
#pragma unroll
            for (int jp = 0; jp < 4; ++jp) {
                int ca = c0 + jp * 2, cb = ca + 1;
                float v0, v1;
                if (n < 128) {
                    v0 = weight[(n * 64 + ca) * 27 + kb];
                    v1 = weight[(n * 64 + cb) * 27 + kb];
                } else {
                    v0 = loraA[(n - 128) * 1728 + ca * 27 + kb];
                    v1 = loraA[(n - 128) * 1728 + cb * 27 + kb];
                }
                u[jp] = (unsigned)f2bf(v0) | ((unsigned)f2bf(v1) << 16);
            }
            uint4 val; val.x = u[0]; val.y = u[1]; val.z = u[2]; val.w = u[3];
            *(uint4*)(wpack + (size_t)gid * 8) = val;
        }
    }
}

__global__ __launch_bounds__(256) void gemm_kernel(const unsigned short* __restrict__ xt,
                                                   const unsigned short* __restrict__ wpack,
                                                   const float* __restrict__ bias,
                                                   float* __restrict__ out,
                                                   unsigned short* __restrict__ cbuf,
                                                   float* __restrict__ low,
                                                   int use_cbuf) {
    __shared__ unsigned short Abuf[2][9216];

    int t = threadIdx.x;
    int wv = t >> 6;
    int lane = t & 63;
    int l16 = lane & 15;
    int quad = lane >> 4;

    int bid = blockIdx.x;
    int tile = ((bid & 7) << 6) | (bid >> 3);
    int b = tile >> 8;
    int d = (tile >> 3) & 31;
    int h = ((tile & 7) << 2) + wv;

    int pbase = (((b * 34 + d) * 34 + h) * 34 + l16) * 64 + quad * 8;

    float4v acc[9][2];
#pragma unroll
    for (int nf = 0; nf < 9; ++nf)
#pragma unroll
        for (int f = 0; f < 2; ++f) acc[nf][f] = (float4v){0.f, 0.f, 0.f, 0.f};

    short8 breg[2][2][2];

    auto prefA = [&](int tap, int buf) {
        const unsigned short* src = wpack + tap * 9216;
        unsigned short* dst = &Abuf[buf][0];
#pragma unroll
        for (int j = 0; j < 4; ++j) {
            int c8 = (t + j * 256) * 8;
            gll16(src + c8, dst + c8);
        }
        if (t < 128) {
            int c8 = (t + 1024) * 8;
            gll16(src + c8, dst + c8);
        }
    };
    auto loadB = [&](int tap, int buf) {
        int ki = tap / 9;
        int kjl = tap - ki * 9;
        int kj = kjl / 3;
        int kl = kjl - kj * 3;
        int koff = ki * 73984 + kj * 2176 + kl * 64;
        const unsigned short* xp = xt + pbase + koff;
        breg[buf][0][0] = *(const short8*)(xp);
        breg[buf][0][1] = *(const short8*)(xp + 1024);
        breg[buf][1][0] = *(const short8*)(xp + 32);
        breg[buf][1][1] = *(const short8*)(xp + 1056);
    };

    prefA(0, 0);
    loadB(0, 0);
    __syncthreads();

    for (int tap = 0; tap < 27; ++tap) {
        int cur = tap & 1, nxt = cur ^ 1;
        if (tap < 26) {
            prefA(tap + 1, nxt);
            loadB(tap + 1, nxt);
        }
        const unsigned short* ab = &Abuf[cur][0] + lane * 8;
#pragma unroll
        for (int ks = 0; ks < 2; ++ks) {
            short8 af[9];
#pragma unroll
            for (int nf = 0; nf < 9; ++nf)
                af[nf] = *(const short8*)(ab + (ks * 9 + nf) * 512);
#pragma unroll
            for (int nf = 0; nf < 9; ++nf) {
                acc[nf][0] = __builtin_amdgcn_mfma_f32_16x16x32_bf16(af[nf], breg[cur][ks][0], acc[nf][0], 0, 0, 0);
                acc[nf][1] = __builtin_amdgcn_mfma_f32_16x16x32_bf16(af[nf], breg[cur][ks][1], acc[nf][1], 0, 0, 0);
            }
        }
        __syncthreads();
    }

#pragma unroll
    for (int f = 0; f < 2; ++f) {
        int w = f * 16 + l16;
        int p = d * 1024 + h * 32 + w;
#pragma unroll
        for (int nf = 0; nf < 9; ++nf) {
#pragma unroll
            for (int r = 0; r < 4; ++r) {
                int o = nf * 16 + quad * 4 + r;
                float v = acc[nf][f][r];
                if (o < 128) {
                    float c = v + bias[o];
                    if (use_cbuf) cbuf[((size_t)(b * 128 + o) << 15) + p] = f2bf(c);
                    else          out[((size_t)(b * 128 + o) << 15) + p] = c;
                } else {
                    low[((size_t)(b * 16 + (o - 128)) << 15) + p] = v;
                }
            }
        }
    }
}

__global__ __launch_bounds__(256) void foldmix_kernel(const float* __restrict__ low,
                                                      const float* __restrict__ loraB,
                                                      const unsigned short* __restrict__ cbuf,
                                                      float* __restrict__ out,
                                                      int use_cbuf) {
    __shared__ float fl[16][128];
    __shared__ float lB[2048];
    int t = threadIdx.x;
    for (int i = t; i < 2048; i += 256) lB[i] = loraB[i];

    int P0 = blockIdx.x * 128;
    int b = P0 >> 15;
    int p0 = P0 & 32767;

    {
        int pair = t & 63;
        int rg = t >> 6;
        int p = p0 + pair * 2;
        int dd0 = p >> 10, hh = (p >> 5) & 31, w0 = p & 31;
        float s[4][2];
#pragma unroll
        for (int r = 0; r < 4; ++r) { s[r][0] = 0.f; s[r][1] = 0.f; }
        const float* bb = low + ((size_t)(b * 16 + rg * 4) << 15);
        for (int dd = -1; dd <= 1; ++dd) {
            int sd = dd0 + dd;
            if ((unsigned)sd >= 32u) continue;
            for (int dh = -1; dh <= 1; ++dh) {
                int sh = hh + dh;
                if ((unsigned)sh >= 32u) continue;
                int base = (sd << 10) + (sh << 5) + w0;
#pragma unroll
                for (int r = 0; r < 4; ++r) {
                    const float* q = bb + ((size_t)r << 15) + base;
                    float vm = (w0 > 0)  ? q[-1] : 0.f;
                    float v0 = q[0], v1 = q[1];
                    float v2 = (w0 < 30) ? q[2] : 0.f;
                    s[r][0] += vm + v0 + v1;
                    s[r][1] += v0 + v1 + v2;
                }
            }
        }
#pragma unroll
        for (int r = 0; r < 4; ++r) {
            fl[rg * 4 + r][pair * 2]     = s[r][0];
            fl[rg * 4 + r][pair * 2 + 1] = s[r][1];
        }
    }
    __syncthreads();

    int wv = t >> 6;
    int lane = t & 63;
    int pl = lane * 2;
    int p = p0 + pl;
    float2 f[16];
#pragma unroll
    for (int r = 0; r < 16; ++r) f[r] = *(const float2*)&fl[r][pl];

    int o0 = wv * 32;
#pragma unroll
    for (int oi = 0; oi < 32; ++oi) {
        int o = o0 + oi;
        float sa = 0.f, sb = 0.f;
#pragma unroll
        for (int r = 0; r < 16; ++r) {
            float lw = lB[o * 16 + r];
            sa += lw * f[r].x;
            sb += lw * f[r].y;
        }
        size_t idx = ((size_t)(b * 128 + o) << 15) + p;
        float cx, cy;
        if (use_cbuf) {
            unsigned int u = *(const unsigned int*)(cbuf + idx);
            cx = __uint_as_float(u << 16);
            cy = __uint_as_float(u & 0xffff0000u);
        } else {
            float2 c = *(const float2*)(out + idx);
            cx = c.x; cy = c.y;
        }
        float2 res;
        res.x = cx + 2.0f * sa;
        res.y = cy + 2.0f * sb;
        *(float2*)(out + idx) = res;
    }
}

extern "C" void kernel_launch(void* const* d_in, const int* in_sizes, int n_in,
                              void* d_out, int out_size, void* d_ws, size_t ws_size,
                              hipStream_t stream) {
    const float* x      = (const float*)d_in[0];
    const float* weight = (const float*)d_in[1];
    const float* bias   = (const float*)d_in[2];
    const float* loraA  = (const float*)d_in[3];
    const float* loraB  = (const float*)d_in[4];
    float* out = (float*)d_out;

    char* ws = (char*)d_ws;
    unsigned short* xt    = (unsigned short*)ws;                  // 10,061,824 B
    unsigned short* wpack = (unsigned short*)(ws + 10061824);     //    497,664 B
    float* low            = (float*)(ws + 10559488);              //  4,194,304 B
    unsigned int* bar     = (unsigned int*)(ws + 14753792);       //        256 B
    unsigned short* cbuf  = (unsigned short*)(ws + 14753792);     // 16,777,216 B (fallback only)

    if (ws_size >= 14754048u) {
        hipMemsetAsync(bar, 0, 256, stream);
        hipLaunchKernelGGL(fused_kernel, dim3(512), dim3(256), 0, stream,
                           x, weight, bias, loraA, loraB, out, xt, wpack, low, bar);
    } else {
        int use_cbuf = (ws_size >= 31531008u) ? 1 : 0;
        hipLaunchKernelGGL(prep_kernel, dim3(1454), dim3(256), 0, stream, x, weight, loraA, xt, wpack);
        hipLaunchKernelGGL(gemm_kernel, dim3(512), dim3(256), 0, stream, xt, wpack, bias, out, cbuf, low, use_cbuf);
        hipLaunchKernelGGL(foldmix_kernel, dim3(512), dim3(256), 0, stream, low, loraB, cbuf, out, use_cbuf);
    }
}

// Round 4
// 202.618 us; speedup vs baseline: 1.6288x; 1.6288x over previous
//
#include <hip/hip_runtime.h>

// x: [2,64,32,32,32] f32 | weight: [128,64,3,3,3] f32 | bias:[128]
// lora_A: [16,1728] | lora_B: [128,16] | out: [2,128,32,32,32] f32 | SCALING = 2.0

typedef __attribute__((ext_vector_type(8))) short short8;
typedef __attribute__((ext_vector_type(4))) float float4v;

#define PV 39304   // 34^3
#define PH 1156    // 34^2

__device__ inline unsigned short f2bf(float f) {
    unsigned int u = __float_as_uint(f);
    unsigned int r = u + 0x7FFFu + ((u >> 16) & 1u);
    return (unsigned short)(r >> 16);
}

// grid = 1024 (transpose) + 308 (halo zero) + 122 (weight pack)
__global__ __launch_bounds__(256) void prep_kernel(const float* __restrict__ x,
                                                   const float* __restrict__ weight,
                                                   const float* __restrict__ loraA,
                                                   unsigned short* __restrict__ xt,
                                                   unsigned short* __restrict__ wpack) {
    int t = threadIdx.x;
    int blk = blockIdx.x;
    if (blk < 1024) {
        __shared__ float tile[64][65];
        int b = blk >> 9;
        int p0 = (blk & 511) * 64;
        int d = p0 >> 10;
        int h0 = (p0 >> 5) & 31;
#pragma unroll
        for (int it = 0; it < 16; ++it) {
            int idx = it * 256 + t;
            int c = idx >> 6, pp = idx & 63;
            tile[c][pp] = x[((size_t)(b * 64 + c) << 15) + p0 + pp];
        }
        __syncthreads();
#pragma unroll
        for (int it = 0; it < 8; ++it) {
            int idx = it * 256 + t;
            int pp = idx >> 5, cp = idx & 31;
            unsigned int u0 = f2bf(tile[cp * 2][pp]);
            unsigned int u1 = f2bf(tile[cp * 2 + 1][pp]);
            int h = h0 + (pp >> 5);
            int w = pp & 31;
            size_t pidx = (size_t)((b * 34 + d + 1) * 34 + h + 1) * 34 + w + 1;
            *(unsigned int*)(xt + pidx * 64 + cp * 2) = u0 | (u1 << 16);
        }
    } else if (blk < 1332) {
        int idx = (blk - 1024) * 256 + t;     // over 2*39304 padded positions
        if (idx < 78608) {
            int b = idx / PV;
            int pp = idx - b * PV;
            int d = pp / PH;
            int r2 = pp - d * PH;
            int h = r2 / 34;
            int w = r2 - h * 34;
            if (d == 0 || d == 33 || h == 0 || h == 33 || w == 0 || w == 33) {
                uint4 z = {0u, 0u, 0u, 0u};
                uint4* dst = (uint4*)(xt + (size_t)idx * 64);
#pragma unroll
                for (int i = 0; i < 8; ++i) dst[i] = z;
            }
        }
    } else {
        int gid = (blk - 1332) * 256 + t;     // 486 frags * 64 lanes = 31104
        if (gid < 31104) {
            int frag = gid >> 6, lane = gid & 63;
            int kb = frag / 18;
            int r18 = frag - kb * 18;
            int ks = r18 / 9;
            int nf = r18 - ks * 9;
            int l16 = lane & 15, quad = lane >> 4;
            int n = nf * 16 + l16;
            int c0 = ks * 32 + quad * 8;
            unsigned int u[4];
#pragma unroll
            for (int jp = 0; jp < 4; ++jp) {
                int ca = c0 + jp * 2, cb = ca + 1;
                float v0, v1;
                if (n < 128) {
                    v0 = weight[(n * 64 + ca) * 27 + kb];
                    v1 = weight[(n * 64 + cb) * 27 + kb];
                } else {
                    v0 = loraA[(n - 128) * 1728 + ca * 27 + kb];
                    v1 = loraA[(n - 128) * 1728 + cb * 27 + kb];
                }
                u[jp] = (unsigned)f2bf(v0) | ((unsigned)f2bf(v1) << 16);
            }
            uint4 val; val.x = u[0]; val.y = u[1]; val.z = u[2]; val.w = u[3];
            *(uint4*)(wpack + (size_t)gid * 8) = val;
        }
    }
}

// 512 blocks x 4 waves. Wave = 1 h-row x 32 w, M = 144 (9 A-frags).
// NO LDS, NO barriers: A-fragments are read per-wave directly from wpack
// (L2-resident, 497KB, laid out in exact per-lane fragment order -> each
// frag load is one coalesced 1KB global_load_dwordx4). Removes the 27
// per-tap vmcnt(0)+s_barrier drains and the LDS pipe bottleneck
// (144 ds_read_b128/CU/tap ~= 19us) of the previous structure.
__global__ __launch_bounds__(256, 2) void gemm_kernel(const unsigned short* __restrict__ xt,
                                                      const unsigned short* __restrict__ wpack,
                                                      const float* __restrict__ bias,
                                                      float* __restrict__ out,
                                                      unsigned short* __restrict__ cbuf,
                                                      float* __restrict__ low,
                                                      int use_cbuf) {
    int t = threadIdx.x;
    int wv = t >> 6;
    int lane = t & 63;
    int l16 = lane & 15;
    int quad = lane >> 4;

    int bid = blockIdx.x;                       // 512
    int tile = ((bid & 7) << 6) | (bid >> 3);   // XCD d-slab locality
    int b = tile >> 8;
    int d = (tile >> 3) & 31;
    int h = ((tile & 7) << 2) + wv;

    int pbase = (((b * 34 + d) * 34 + h) * 34 + l16) * 64 + quad * 8;
    const unsigned short* ap = wpack + lane * 8;    // lane's A-fragment base

    float4v acc[9][2];
#pragma unroll
    for (int nf = 0; nf < 9; ++nf)
#pragma unroll
        for (int f = 0; f < 2; ++f) acc[nf][f] = (float4v){0.f, 0.f, 0.f, 0.f};

    for (int tap = 0; tap < 27; ++tap) {
        int ki = tap / 9;
        int kjl = tap - ki * 9;
        int kj = kjl / 3;
        int kl = kjl - kj * 3;
        int koff = ki * 73984 + kj * 2176 + kl * 64;
        const unsigned short* xp = xt + pbase + koff;

        // B: 4 coalesced 16B loads (xt, mostly L2-hot)
        short8 b00 = *(const short8*)(xp);
        short8 b01 = *(const short8*)(xp + 1024);
        short8 b10 = *(const short8*)(xp + 32);
        short8 b11 = *(const short8*)(xp + 1056);

        // A: 18 coalesced 1KB wave-loads from wpack (L2-resident broadcast)
        const unsigned short* at = ap + tap * 9216;
        short8 af[2][9];
#pragma unroll
        for (int ks = 0; ks < 2; ++ks)
#pragma unroll
            for (int nf = 0; nf < 9; ++nf)
                af[ks][nf] = *(const short8*)(at + (ks * 9 + nf) * 512);

#pragma unroll
        for (int nf = 0; nf < 9; ++nf) {
            acc[nf][0] = __builtin_amdgcn_mfma_f32_16x16x32_bf16(af[0][nf], b00, acc[nf][0], 0, 0, 0);
            acc[nf][1] = __builtin_amdgcn_mfma_f32_16x16x32_bf16(af[0][nf], b01, acc[nf][1], 0, 0, 0);
        }
#pragma unroll
        for (int nf = 0; nf < 9; ++nf) {
            acc[nf][0] = __builtin_amdgcn_mfma_f32_16x16x32_bf16(af[1][nf], b10, acc[nf][0], 0, 0, 0);
            acc[nf][1] = __builtin_amdgcn_mfma_f32_16x16x32_bf16(af[1][nf], b11, acc[nf][1], 0, 0, 0);
        }
    }

#pragma unroll
    for (int f = 0; f < 2; ++f) {
        int w = f * 16 + l16;
        int p = d * 1024 + h * 32 + w;
#pragma unroll
        for (int nf = 0; nf < 9; ++nf) {
#pragma unroll
            for (int r = 0; r < 4; ++r) {
                int o = nf * 16 + quad * 4 + r;
                float v = acc[nf][f][r];
                if (o < 128) {
                    float c = v + bias[o];
                    if (use_cbuf) cbuf[((size_t)(b * 128 + o) << 15) + p] = f2bf(c);
                    else          out[((size_t)(b * 128 + o) << 15) + p] = c;
                } else {
                    low[((size_t)(b * 16 + (o - 128)) << 15) + p] = v;
                }
            }
        }
    }
}

// 512 blocks x 128 positions: fold low -> fl[16][128] (2 pos/thread, shared
// 4-wide w-window), then out = cbuf + 2 * lora_B . fl with float2 stores.
__global__ __launch_bounds__(256) void foldmix_kernel(const float* __restrict__ low,
                                                      const float* __restrict__ loraB,
                                                      const unsigned short* __restrict__ cbuf,
                                                      float* __restrict__ out,
                                                      int use_cbuf) {
    __shared__ float fl[16][128];
    __shared__ float lB[2048];
    int t = threadIdx.x;
    for (int i = t; i < 2048; i += 256) lB[i] = loraB[i];

    int P0 = blockIdx.x * 128;
    int b = P0 >> 15;
    int p0 = P0 & 32767;

    {
        int pair = t & 63;           // 2 consecutive w positions
        int rg = t >> 6;             // 4 ranks
        int p = p0 + pair * 2;
        int dd0 = p >> 10, hh = (p >> 5) & 31, w0 = p & 31;   // w0 even
        float s[4][2];
#pragma unroll
        for (int r = 0; r < 4; ++r) { s[r][0] = 0.f; s[r][1] = 0.f; }
        const float* bb = low + ((size_t)(b * 16 + rg * 4) << 15);
        for (int dd = -1; dd <= 1; ++dd) {
            int sd = dd0 + dd;
            if ((unsigned)sd >= 32u) continue;
            for (int dh = -1; dh <= 1; ++dh) {
                int sh = hh + dh;
                if ((unsigned)sh >= 32u) continue;
                int base = (sd << 10) + (sh << 5) + w0;
#pragma unroll
                for (int r = 0; r < 4; ++r) {
                    const float* q = bb + ((size_t)r << 15) + base;
                    float vm = (w0 > 0)  ? q[-1] : 0.f;
                    float v0 = q[0], v1 = q[1];
                    float v2 = (w0 < 30) ? q[2] : 0.f;
                    s[r][0] += vm + v0 + v1;
                    s[r][1] += v0 + v1 + v2;
                }
            }
        }
#pragma unroll
        for (int r = 0; r < 4; ++r) {
            fl[rg * 4 + r][pair * 2]     = s[r][0];
            fl[rg * 4 + r][pair * 2 + 1] = s[r][1];
        }
    }
    __syncthreads();

    int wv = t >> 6;
    int lane = t & 63;
    int pl = lane * 2;
    int p = p0 + pl;
    float2 f[16];
#pragma unroll
    for (int r = 0; r < 16; ++r) f[r] = *(const float2*)&fl[r][pl];

    int o0 = wv * 32;
#pragma unroll
    for (int oi = 0; oi < 32; ++oi) {
        int o = o0 + oi;
        float sa = 0.f, sb = 0.f;
#pragma unroll
        for (int r = 0; r < 16; ++r) {
            float lw = lB[o * 16 + r];
            sa += lw * f[r].x;
            sb += lw * f[r].y;
        }
        size_t idx = ((size_t)(b * 128 + o) << 15) + p;
        float cx, cy;
        if (use_cbuf) {
            unsigned int u = *(const unsigned int*)(cbuf + idx);
            cx = __uint_as_float(u << 16);
            cy = __uint_as_float(u & 0xffff0000u);
        } else {
            float2 c = *(const float2*)(out + idx);
            cx = c.x; cy = c.y;
        }
        float2 res;
        res.x = cx + 2.0f * sa;
        res.y = cy + 2.0f * sb;
        *(float2*)(out + idx) = res;
    }
}

extern "C" void kernel_launch(void* const* d_in, const int* in_sizes, int n_in,
                              void* d_out, int out_size, void* d_ws, size_t ws_size,
                              hipStream_t stream) {
    const float* x      = (const float*)d_in[0];
    const float* weight = (const float*)d_in[1];
    const float* bias   = (const float*)d_in[2];
    const float* loraA  = (const float*)d_in[3];
    const float* loraB  = (const float*)d_in[4];
    float* out = (float*)d_out;

    char* ws = (char*)d_ws;
    unsigned short* xt    = (unsigned short*)ws;                  // 10,061,824 B
    unsigned short* wpack = (unsigned short*)(ws + 10061824);     //    497,664 B
    float* low            = (float*)(ws + 10559488);              //  4,194,304 B
    unsigned short* cbuf  = (unsigned short*)(ws + 14753792);     // 16,777,216 B
    int use_cbuf = (ws_size >= 31531008u) ? 1 : 0;

    hipLaunchKernelGGL(prep_kernel, dim3(1454), dim3(256), 0, stream, x, weight, loraA, xt, wpack);
    hipLaunchKernelGGL(gemm_kernel, dim3(512), dim3(256), 0, stream, xt, wpack, bias, out, cbuf, low, use_cbuf);
    hipLaunchKernelGGL(foldmix_kernel, dim3(512), dim3(256), 0, stream, low, loraB, cbuf, out, use_cbuf);
}

// Round 5
// 194.097 us; speedup vs baseline: 1.7003x; 1.0439x over previous
//
#include <hip/hip_runtime.h>

// x: [2,64,32,32,32] f32 | weight: [128,64,3,3,3] f32 | bias:[128]
// lora_A: [16,1728] | lora_B: [128,16] | out: [2,128,32,32,32] f32 | SCALING = 2.0

typedef __attribute__((ext_vector_type(8))) short short8;
typedef __attribute__((ext_vector_type(4))) float float4v;

#define PV 39304   // 34^3
#define PH 1156    // 34^2

__device__ inline unsigned short f2bf(float f) {
    unsigned int u = __float_as_uint(f);
    unsigned int r = u + 0x7FFFu + ((u >> 16) & 1u);
    return (unsigned short)(r >> 16);
}

__device__ inline void gll16(const void* g, void* l) {
    __builtin_amdgcn_global_load_lds(
        (const __attribute__((address_space(1))) unsigned int*)g,
        (__attribute__((address_space(3))) unsigned int*)l, 16, 0, 0);
}

// grid = 1024 (transpose) + 308 (halo zero) + 122 (weight pack)
__global__ __launch_bounds__(256) void prep_kernel(const float* __restrict__ x,
                                                   const float* __restrict__ weight,
                                                   const float* __restrict__ loraA,
                                                   unsigned short* __restrict__ xt,
                                                   unsigned short* __restrict__ wpack) {
    int t = threadIdx.x;
    int blk = blockIdx.x;
    if (blk < 1024) {
        __shared__ float tile[64][65];
        int b = blk >> 9;
        int p0 = (blk & 511) * 64;
        int d = p0 >> 10;
        int h0 = (p0 >> 5) & 31;
#pragma unroll
        for (int it = 0; it < 16; ++it) {
            int idx = it * 256 + t;
            int c = idx >> 6, pp = idx & 63;
            tile[c][pp] = x[((size_t)(b * 64 + c) << 15) + p0 + pp];
        }
        __syncthreads();
#pragma unroll
        for (int it = 0; it < 8; ++it) {
            int idx = it * 256 + t;
            int pp = idx >> 5, cp = idx & 31;
            unsigned int u0 = f2bf(tile[cp * 2][pp]);
            unsigned int u1 = f2bf(tile[cp * 2 + 1][pp]);
            int h = h0 + (pp >> 5);
            int w = pp & 31;
            size_t pidx = (size_t)((b * 34 + d + 1) * 34 + h + 1) * 34 + w + 1;
            *(unsigned int*)(xt + pidx * 64 + cp * 2) = u0 | (u1 << 16);
        }
    } else if (blk < 1332) {
        int idx = (blk - 1024) * 256 + t;     // over 2*39304 padded positions
        if (idx < 78608) {
            int b = idx / PV;
            int pp = idx - b * PV;
            int d = pp / PH;
            int r2 = pp - d * PH;
            int h = r2 / 34;
            int w = r2 - h * 34;
            if (d == 0 || d == 33 || h == 0 || h == 33 || w == 0 || w == 33) {
                uint4 z = {0u, 0u, 0u, 0u};
                uint4* dst = (uint4*)(xt + (size_t)idx * 64);
#pragma unroll
                for (int i = 0; i < 8; ++i) dst[i] = z;
            }
        }
    } else {
        int gid = (blk - 1332) * 256 + t;     // 486 frags * 64 lanes = 31104
        if (gid < 31104) {
            int frag = gid >> 6, lane = gid & 63;
            int kb = frag / 18;
            int r18 = frag - kb * 18;
            int ks = r18 / 9;
            int nf = r18 - ks * 9;
            int l16 = lane & 15, quad = lane >> 4;
            int n = nf * 16 + l16;
            int c0 = ks * 32 + quad * 8;
            unsigned int u[4];
#pragma unroll
            for (int jp = 0; jp < 4; ++jp) {
                int ca = c0 + jp * 2, cb = ca + 1;
                float v0, v1;
                if (n < 128) {
                    v0 = weight[(n * 64 + ca) * 27 + kb];
                    v1 = weight[(n * 64 + cb) * 27 + kb];
                } else {
                    v0 = loraA[(n - 128) * 1728 + ca * 27 + kb];
                    v1 = loraA[(n - 128) * 1728 + cb * 27 + kb];
                }
                u[jp] = (unsigned)f2bf(v0) | ((unsigned)f2bf(v1) << 16);
            }
            uint4 val; val.x = u[0]; val.y = u[1]; val.z = u[2]; val.w = u[3];
            *(uint4*)(wpack + (size_t)gid * 8) = val;
        }
    }
}

// 256 blocks x 4 waves. Wave = 2 h-rows x 32 w (N=64), M = 144 (9 A-frags).
// A staged in LDS (dbuf, global_load_lds prefetch 1 tap ahead, shared by 4
// waves); B per-lane global with register dbuf. Barrier per tap.
// N=64/wave halves the per-CU LDS read traffic vs the N=32 version
// (18 ds_read_b128 per wave-tap now feed 72 MFMAs instead of 36).
// 1 block/CU -> launch_bounds(256,1) uncaps the register allocator
// (acc 144 + af 36 + breg 64 ~ 264 regs, under the 512 spill limit).
__global__ __launch_bounds__(256, 1) void gemm_kernel(const unsigned short* __restrict__ xt,
                                                      const unsigned short* __restrict__ wpack,
                                                      const float* __restrict__ bias,
                                                      float* __restrict__ out,
                                                      unsigned short* __restrict__ cbuf,
                                                      float* __restrict__ low,
                                                      int use_cbuf) {
    __shared__ unsigned short Abuf[2][9216];   // 2 x 18432 B = tap's 18 frags

    int t = threadIdx.x;
    int wv = t >> 6;
    int lane = t & 63;
    int l16 = lane & 15;
    int quad = lane >> 4;

    int bid = blockIdx.x;                       // 256
    int tile = ((bid & 7) << 5) | (bid >> 3);   // XCD swizzle (bijective on 256)
    int b = tile >> 7;
    int d = (tile >> 2) & 31;
    int h0 = ((tile & 3) << 3) + wv * 2;        // wave covers rows h0, h0+1

    int pbase = (((b * 34 + d) * 34 + h0) * 34 + l16) * 64 + quad * 8;

    float4v acc[9][4];
#pragma unroll
    for (int nf = 0; nf < 9; ++nf)
#pragma unroll
        for (int f = 0; f < 4; ++f) acc[nf][f] = (float4v){0.f, 0.f, 0.f, 0.f};

    short8 breg[2][2][4];    // [buf][ks][f]  f = (row<<1)|whalf

    auto prefA = [&](int tap, int buf) {
        const unsigned short* src = wpack + tap * 9216;   // 18432 B per tap
        unsigned short* dst = &Abuf[buf][0];
#pragma unroll
        for (int j = 0; j < 4; ++j) {
            int c8 = (t + j * 256) * 8;
            gll16(src + c8, dst + c8);
        }
        if (t < 128) {
            int c8 = (t + 1024) * 8;
            gll16(src + c8, dst + c8);
        }
    };
    auto loadB = [&](int tap, int buf) {
        int ki = tap / 9;
        int kjl = tap - ki * 9;
        int kj = kjl / 3;
        int kl = kjl - kj * 3;
        int koff = ki * 73984 + kj * 2176 + kl * 64;
        const unsigned short* xp = xt + pbase + koff;
        breg[buf][0][0] = *(const short8*)(xp);            // row0 w0-15
        breg[buf][0][1] = *(const short8*)(xp + 1024);     // row0 w16-31
        breg[buf][0][2] = *(const short8*)(xp + 2176);     // row1 w0-15
        breg[buf][0][3] = *(const short8*)(xp + 3200);     // row1 w16-31
        breg[buf][1][0] = *(const short8*)(xp + 32);       // ks=1 (cin+32)
        breg[buf][1][1] = *(const short8*)(xp + 1056);
        breg[buf][1][2] = *(const short8*)(xp + 2208);
        breg[buf][1][3] = *(const short8*)(xp + 3232);
    };

    prefA(0, 0);
    loadB(0, 0);
    __syncthreads();

    for (int tap = 0; tap < 27; ++tap) {
        int cur = tap & 1, nxt = cur ^ 1;
        if (tap < 26) {
            prefA(tap + 1, nxt);
            loadB(tap + 1, nxt);
        }
        const unsigned short* ab = &Abuf[cur][0] + lane * 8;
#pragma unroll
        for (int ks = 0; ks < 2; ++ks) {
            short8 af[9];
#pragma unroll
            for (int nf = 0; nf < 9; ++nf)
                af[nf] = *(const short8*)(ab + (ks * 9 + nf) * 512);
#pragma unroll
            for (int nf = 0; nf < 9; ++nf) {
#pragma unroll
                for (int f = 0; f < 4; ++f)
                    acc[nf][f] = __builtin_amdgcn_mfma_f32_16x16x32_bf16(af[nf], breg[cur][ks][f], acc[nf][f], 0, 0, 0);
            }
        }
        __syncthreads();
    }

#pragma unroll
    for (int f = 0; f < 4; ++f) {
        int hh = h0 + (f >> 1);
        int w = (f & 1) * 16 + l16;
        int p = d * 1024 + hh * 32 + w;
#pragma unroll
        for (int nf = 0; nf < 9; ++nf) {
#pragma unroll
            for (int r = 0; r < 4; ++r) {
                int o = nf * 16 + quad * 4 + r;
                float v = acc[nf][f][r];
                if (o < 128) {
                    float c = v + bias[o];
                    if (use_cbuf) cbuf[((size_t)(b * 128 + o) << 15) + p] = f2bf(c);
                    else          out[((size_t)(b * 128 + o) << 15) + p] = c;
                } else {
                    low[((size_t)(b * 16 + (o - 128)) << 15) + p] = v;
                }
            }
        }
    }
}

// 512 blocks x 128 positions: fold low -> fl[16][128] (2 pos/thread, shared
// 4-wide w-window), then out = cbuf + 2 * lora_B . fl with float2 stores.
__global__ __launch_bounds__(256) void foldmix_kernel(const float* __restrict__ low,
                                                      const float* __restrict__ loraB,
                                                      const unsigned short* __restrict__ cbuf,
                                                      float* __restrict__ out,
                                                      int use_cbuf) {
    __shared__ float fl[16][128];
    __shared__ float lB[2048];
    int t = threadIdx.x;
    for (int i = t; i < 2048; i += 256) lB[i] = loraB[i];

    int P0 = blockIdx.x * 128;
    int b = P0 >> 15;
    int p0 = P0 & 32767;

    {
        int pair = t & 63;           // 2 consecutive w positions
        int rg = t >> 6;             // 4 ranks
        int p = p0 + pair * 2;
        int dd0 = p >> 10, hh = (p >> 5) & 31, w0 = p & 31;   // w0 even
        float s[4][2];
#pragma unroll
        for (int r = 0; r < 4; ++r) { s[r][0] = 0.f; s[r][1] = 0.f; }
        const float* bb = low + ((size_t)(b * 16 + rg * 4) << 15);
        for (int dd = -1; dd <= 1; ++dd) {
            int sd = dd0 + dd;
            if ((unsigned)sd >= 32u) continue;
            for (int dh = -1; dh <= 1; ++dh) {
                int sh = hh + dh;
                if ((unsigned)sh >= 32u) continue;
                int base = (sd << 10) + (sh << 5) + w0;
#pragma unroll
                for (int r = 0; r < 4; ++r) {
                    const float* q = bb + ((size_t)r << 15) + base;
                    float vm = (w0 > 0)  ? q[-1] : 0.f;
                    float v0 = q[0], v1 = q[1];
                    float v2 = (w0 < 30) ? q[2] : 0.f;
                    s[r][0] += vm + v0 + v1;
                    s[r][1] += v0 + v1 + v2;
                }
            }
        }
#pragma unroll
        for (int r = 0; r < 4; ++r) {
            fl[rg * 4 + r][pair * 2]     = s[r][0];
            fl[rg * 4 + r][pair * 2 + 1] = s[r][1];
        }
    }
    __syncthreads();

    int wv = t >> 6;
    int lane = t & 63;
    int pl = lane * 2;
    int p = p0 + pl;
    float2 f[16];
#pragma unroll
    for (int r = 0; r < 16; ++r) f[r] = *(const float2*)&fl[r][pl];

    int o0 = wv * 32;
#pragma unroll
    for (int oi = 0; oi < 32; ++oi) {
        int o = o0 + oi;
        float sa = 0.f, sb = 0.f;
#pragma unroll
        for (int r = 0; r < 16; ++r) {
            float lw = lB[o * 16 + r];
            sa += lw * f[r].x;
            sb += lw * f[r].y;
        }
        size_t idx = ((size_t)(b * 128 + o) << 15) + p;
        float cx, cy;
        if (use_cbuf) {
            unsigned int u = *(const unsigned int*)(cbuf + idx);
            cx = __uint_as_float(u << 16);
            cy = __uint_as_float(u & 0xffff0000u);
        } else {
            float2 c = *(const float2*)(out + idx);
            cx = c.x; cy = c.y;
        }
        float2 res;
        res.x = cx + 2.0f * sa;
        res.y = cy + 2.0f * sb;
        *(float2*)(out + idx) = res;
    }
}

extern "C" void kernel_launch(void* const* d_in, const int* in_sizes, int n_in,
                              void* d_out, int out_size, void* d_ws, size_t ws_size,
                              hipStream_t stream) {
    const float* x      = (const float*)d_in[0];
    const float* weight = (const float*)d_in[1];
    const float* bias   = (const float*)d_in[2];
    const float* loraA  = (const float*)d_in[3];
    const float* loraB  = (const float*)d_in[4];
    float* out = (float*)d_out;

    char* ws = (char*)d_ws;
    unsigned short* xt    = (unsigned short*)ws;                  // 10,061,824 B
    unsigned short* wpack = (unsigned short*)(ws + 10061824);     //    497,664 B
    float* low            = (float*)(ws + 10559488);              //  4,194,304 B
    unsigned short* cbuf  = (unsigned short*)(ws + 14753792);     // 16,777,216 B
    int use_cbuf = (ws_size >= 31531008u) ? 1 : 0;

    hipLaunchKernelGGL(prep_kernel, dim3(1454), dim3(256), 0, stream, x, weight, loraA, xt, wpack);
    hipLaunchKernelGGL(gemm_kernel, dim3(256), dim3(256), 0, stream, xt, wpack, bias, out, cbuf, low, use_cbuf);
    hipLaunchKernelGGL(foldmix_kernel, dim3(512), dim3(256), 0, stream, low, loraB, cbuf, out, use_cbuf);
}

// Round 6
// 165.926 us; speedup vs baseline: 1.9889x; 1.1698x over previous
//
#include <hip/hip_runtime.h>

// x: [2,64,32,32,32] f32 | weight: [128,64,3,3,3] f32 | bias:[128]
// lora_A: [16,1728] | lora_B: [128,16] | out: [2,128,32,32,32] f32 | SCALING = 2.0

typedef __attribute__((ext_vector_type(8))) short short8;
typedef __attribute__((ext_vector_type(4))) float float4v;

#define PV 39304   // 34^3
#define PH 1156    // 34^2

__device__ inline unsigned short f2bf(float f) {
    unsigned int u = __float_as_uint(f);
    unsigned int r = u + 0x7FFFu + ((u >> 16) & 1u);
    return (unsigned short)(r >> 16);
}

__device__ inline void gll16(const void* g, void* l) {
    __builtin_amdgcn_global_load_lds(
        (const __attribute__((address_space(1))) unsigned int*)g,
        (__attribute__((address_space(3))) unsigned int*)l, 16, 0, 0);
}

// grid = 1024 (transpose) + 308 (halo zero) + 122 (weight pack)
__global__ __launch_bounds__(256) void prep_kernel(const float* __restrict__ x,
                                                   const float* __restrict__ weight,
                                                   const float* __restrict__ loraA,
                                                   unsigned short* __restrict__ xt,
                                                   unsigned short* __restrict__ wpack) {
    int t = threadIdx.x;
    int blk = blockIdx.x;
    if (blk < 1024) {
        __shared__ float tile[64][65];
        int b = blk >> 9;
        int p0 = (blk & 511) * 64;
        int d = p0 >> 10;
        int h0 = (p0 >> 5) & 31;
#pragma unroll
        for (int it = 0; it < 16; ++it) {
            int idx = it * 256 + t;
            int c = idx >> 6, pp = idx & 63;
            tile[c][pp] = x[((size_t)(b * 64 + c) << 15) + p0 + pp];
        }
        __syncthreads();
#pragma unroll
        for (int it = 0; it < 8; ++it) {
            int idx = it * 256 + t;
            int pp = idx >> 5, cp = idx & 31;
            unsigned int u0 = f2bf(tile[cp * 2][pp]);
            unsigned int u1 = f2bf(tile[cp * 2 + 1][pp]);
            int h = h0 + (pp >> 5);
            int w = pp & 31;
            size_t pidx = (size_t)((b * 34 + d + 1) * 34 + h + 1) * 34 + w + 1;
            *(unsigned int*)(xt + pidx * 64 + cp * 2) = u0 | (u1 << 16);
        }
    } else if (blk < 1332) {
        int idx = (blk - 1024) * 256 + t;     // over 2*39304 padded positions
        if (idx < 78608) {
            int b = idx / PV;
            int pp = idx - b * PV;
            int d = pp / PH;
            int r2 = pp - d * PH;
            int h = r2 / 34;
            int w = r2 - h * 34;
            if (d == 0 || d == 33 || h == 0 || h == 33 || w == 0 || w == 33) {
                uint4 z = {0u, 0u, 0u, 0u};
                uint4* dst = (uint4*)(xt + (size_t)idx * 64);
#pragma unroll
                for (int i = 0; i < 8; ++i) dst[i] = z;
            }
        }
    } else {
        int gid = (blk - 1332) * 256 + t;     // 486 frags * 64 lanes = 31104
        if (gid < 31104) {
            int frag = gid >> 6, lane = gid & 63;
            int kb = frag / 18;
            int r18 = frag - kb * 18;
            int ks = r18 / 9;
            int nf = r18 - ks * 9;
            int l16 = lane & 15, quad = lane >> 4;
            int n = nf * 16 + l16;
            int c0 = ks * 32 + quad * 8;
            unsigned int u[4];
#pragma unroll
            for (int jp = 0; jp < 4; ++jp) {
                int ca = c0 + jp * 2, cb = ca + 1;
                float v0, v1;
                if (n < 128) {
                    v0 = weight[(n * 64 + ca) * 27 + kb];
                    v1 = weight[(n * 64 + cb) * 27 + kb];
                } else {
                    v0 = loraA[(n - 128) * 1728 + ca * 27 + kb];
                    v1 = loraA[(n - 128) * 1728 + cb * 27 + kb];
                }
                u[jp] = (unsigned)f2bf(v0) | ((unsigned)f2bf(v1) << 16);
            }
            uint4 val; val.x = u[0]; val.y = u[1]; val.z = u[2]; val.w = u[3];
            *(uint4*)(wpack + (size_t)gid * 8) = val;
        }
    }
}

// 256 blocks x 4 waves. Wave = 2 h-rows x 32 w (N=64), M = 144 (9 A-frags).
// A staged in LDS (dbuf, global_load_lds prefetch 1 tap ahead); B in two
// STATICALLY-NAMED register sets breg0/breg1 (tap loop unrolled by 2) --
// runtime-indexed breg[cur] demoted the whole buffer to scratch (rule #20;
// round-5 WRITE_SIZE 252MB = 27 taps x 128B/lane scratch traffic).
__global__ __launch_bounds__(256, 1) void gemm_kernel(const unsigned short* __restrict__ xt,
                                                      const unsigned short* __restrict__ wpack,
                                                      const float* __restrict__ bias,
                                                      float* __restrict__ out,
                                                      unsigned short* __restrict__ cbuf,
                                                      float* __restrict__ low,
                                                      int use_cbuf) {
    __shared__ unsigned short Abuf[2][9216];   // 2 x 18432 B = tap's 18 frags

    int t = threadIdx.x;
    int wv = t >> 6;
    int lane = t & 63;
    int l16 = lane & 15;
    int quad = lane >> 4;

    int bid = blockIdx.x;                       // 256
    int tile = ((bid & 7) << 5) | (bid >> 3);   // XCD swizzle (bijective on 256)
    int b = tile >> 7;
    int d = (tile >> 2) & 31;
    int h0 = ((tile & 3) << 3) + wv * 2;        // wave covers rows h0, h0+1

    int pbase = (((b * 34 + d) * 34 + h0) * 34 + l16) * 64 + quad * 8;

    float4v acc[9][4];
#pragma unroll
    for (int nf = 0; nf < 9; ++nf)
#pragma unroll
        for (int f = 0; f < 4; ++f) acc[nf][f] = (float4v){0.f, 0.f, 0.f, 0.f};

    short8 breg0[2][4];    // [ks][f]  f = (row<<1)|whalf  -- static names only
    short8 breg1[2][4];

    auto prefA = [&](int tap, int buf) {
        const unsigned short* src = wpack + tap * 9216;   // 18432 B per tap
        unsigned short* dst = &Abuf[buf][0];
#pragma unroll
        for (int j = 0; j < 4; ++j) {
            int c8 = (t + j * 256) * 8;
            gll16(src + c8, dst + c8);
        }
        if (t < 128) {
            int c8 = (t + 1024) * 8;
            gll16(src + c8, dst + c8);
        }
    };
    auto loadB = [&](int tap, short8 (&br)[2][4]) {
        int ki = tap / 9;
        int kjl = tap - ki * 9;
        int kj = kjl / 3;
        int kl = kjl - kj * 3;
        int koff = ki * 73984 + kj * 2176 + kl * 64;
        const unsigned short* xp = xt + pbase + koff;
        br[0][0] = *(const short8*)(xp);            // row0 w0-15
        br[0][1] = *(const short8*)(xp + 1024);     // row0 w16-31
        br[0][2] = *(const short8*)(xp + 2176);     // row1 w0-15
        br[0][3] = *(const short8*)(xp + 3200);     // row1 w16-31
        br[1][0] = *(const short8*)(xp + 32);       // ks=1 (cin+32)
        br[1][1] = *(const short8*)(xp + 1056);
        br[1][2] = *(const short8*)(xp + 2208);
        br[1][3] = *(const short8*)(xp + 3232);
    };
    auto compute = [&](const unsigned short* abase, const short8 (&br)[2][4]) {
        const unsigned short* ab = abase + lane * 8;
#pragma unroll
        for (int ks = 0; ks < 2; ++ks) {
            short8 af[9];
#pragma unroll
            for (int nf = 0; nf < 9; ++nf)
                af[nf] = *(const short8*)(ab + (ks * 9 + nf) * 512);
#pragma unroll
            for (int nf = 0; nf < 9; ++nf) {
#pragma unroll
                for (int f = 0; f < 4; ++f)
                    acc[nf][f] = __builtin_amdgcn_mfma_f32_16x16x32_bf16(af[nf], br[ks][f], acc[nf][f], 0, 0, 0);
            }
        }
    };

    prefA(0, 0);
    loadB(0, breg0);
    __syncthreads();

    for (int tt = 0; tt < 13; ++tt) {
        int tap = tt * 2;
        prefA(tap + 1, 1);
        loadB(tap + 1, breg1);
        compute(&Abuf[0][0], breg0);       // tap (even), breg0/Abuf0
        __syncthreads();
        prefA(tap + 2, 0);
        loadB(tap + 2, breg0);
        compute(&Abuf[1][0], breg1);       // tap+1 (odd), breg1/Abuf1
        __syncthreads();
    }
    compute(&Abuf[0][0], breg0);           // tap 26

#pragma unroll
    for (int f = 0; f < 4; ++f) {
        int hh = h0 + (f >> 1);
        int w = (f & 1) * 16 + l16;
        int p = d * 1024 + hh * 32 + w;
#pragma unroll
        for (int nf = 0; nf < 9; ++nf) {
#pragma unroll
            for (int r = 0; r < 4; ++r) {
                int o = nf * 16 + quad * 4 + r;
                float v = acc[nf][f][r];
                if (o < 128) {
                    float c = v + bias[o];
                    if (use_cbuf) cbuf[((size_t)(b * 128 + o) << 15) + p] = f2bf(c);
                    else          out[((size_t)(b * 128 + o) << 15) + p] = c;
                } else {
                    low[((size_t)(b * 16 + (o - 128)) << 15) + p] = v;
                }
            }
        }
    }
}

// 512 blocks x 128 positions: fold low -> fl[16][128] (2 pos/thread, shared
// 4-wide w-window), then out = cbuf + 2 * lora_B . fl with float2 stores.
__global__ __launch_bounds__(256) void foldmix_kernel(const float* __restrict__ low,
                                                      const float* __restrict__ loraB,
                                                      const unsigned short* __restrict__ cbuf,
                                                      float* __restrict__ out,
                                                      int use_cbuf) {
    __shared__ float fl[16][128];
    __shared__ float lB[2048];
    int t = threadIdx.x;
    for (int i = t; i < 2048; i += 256) lB[i] = loraB[i];

    int P0 = blockIdx.x * 128;
    int b = P0 >> 15;
    int p0 = P0 & 32767;

    {
        int pair = t & 63;           // 2 consecutive w positions
        int rg = t >> 6;             // 4 ranks
        int p = p0 + pair * 2;
        int dd0 = p >> 10, hh = (p >> 5) & 31, w0 = p & 31;   // w0 even
        float s[4][2];
#pragma unroll
        for (int r = 0; r < 4; ++r) { s[r][0] = 0.f; s[r][1] = 0.f; }
        const float* bb = low + ((size_t)(b * 16 + rg * 4) << 15);
        for (int dd = -1; dd <= 1; ++dd) {
            int sd = dd0 + dd;
            if ((unsigned)sd >= 32u) continue;
            for (int dh = -1; dh <= 1; ++dh) {
                int sh = hh + dh;
                if ((unsigned)sh >= 32u) continue;
                int base = (sd << 10) + (sh << 5) + w0;
#pragma unroll
                for (int r = 0; r < 4; ++r) {
                    const float* q = bb + ((size_t)r << 15) + base;
                    float vm = (w0 > 0)  ? q[-1] : 0.f;
                    float v0 = q[0], v1 = q[1];
                    float v2 = (w0 < 30) ? q[2] : 0.f;
                    s[r][0] += vm + v0 + v1;
                    s[r][1] += v0 + v1 + v2;
                }
            }
        }
#pragma unroll
        for (int r = 0; r < 4; ++r) {
            fl[rg * 4 + r][pair * 2]     = s[r][0];
            fl[rg * 4 + r][pair * 2 + 1] = s[r][1];
        }
    }
    __syncthreads();

    int wv = t >> 6;
    int lane = t & 63;
    int pl = lane * 2;
    int p = p0 + pl;
    float2 f[16];
#pragma unroll
    for (int r = 0; r < 16; ++r) f[r] = *(const float2*)&fl[r][pl];

    int o0 = wv * 32;
#pragma unroll
    for (int oi = 0; oi < 32; ++oi) {
        int o = o0 + oi;
        float sa = 0.f, sb = 0.f;
#pragma unroll
        for (int r = 0; r < 16; ++r) {
            float lw = lB[o * 16 + r];
            sa += lw * f[r].x;
            sb += lw * f[r].y;
        }
        size_t idx = ((size_t)(b * 128 + o) << 15) + p;
        float cx, cy;
        if (use_cbuf) {
            unsigned int u = *(const unsigned int*)(cbuf + idx);
            cx = __uint_as_float(u << 16);
            cy = __uint_as_float(u & 0xffff0000u);
        } else {
            float2 c = *(const float2*)(out + idx);
            cx = c.x; cy = c.y;
        }
        float2 res;
        res.x = cx + 2.0f * sa;
        res.y = cy + 2.0f * sb;
        *(float2*)(out + idx) = res;
    }
}

extern "C" void kernel_launch(void* const* d_in, const int* in_sizes, int n_in,
                              void* d_out, int out_size, void* d_ws, size_t ws_size,
                              hipStream_t stream) {
    const float* x      = (const float*)d_in[0];
    const float* weight = (const float*)d_in[1];
    const float* bias   = (const float*)d_in[2];
    const float* loraA  = (const float*)d_in[3];
    const float* loraB  = (const float*)d_in[4];
    float* out = (float*)d_out;

    char* ws = (char*)d_ws;
    unsigned short* xt    = (unsigned short*)ws;                  // 10,061,824 B
    unsigned short* wpack = (unsigned short*)(ws + 10061824);     //    497,664 B
    float* low            = (float*)(ws + 10559488);              //  4,194,304 B
    unsigned short* cbuf  = (unsigned short*)(ws + 14753792);     // 16,777,216 B
    int use_cbuf = (ws_size >= 31531008u) ? 1 : 0;

    hipLaunchKernelGGL(prep_kernel, dim3(1454), dim3(256), 0, stream, x, weight, loraA, xt, wpack);
    hipLaunchKernelGGL(gemm_kernel, dim3(256), dim3(256), 0, stream, xt, wpack, bias, out, cbuf, low, use_cbuf);
    hipLaunchKernelGGL(foldmix_kernel, dim3(512), dim3(256), 0, stream, low, loraB, cbuf, out, use_cbuf);
}